// Round 4
// baseline (645.460 us; speedup 1.0000x reference)
//
#include <hip/hip_runtime.h>
#include <stdint.h>

typedef unsigned short u16;
typedef short bf16x8 __attribute__((ext_vector_type(8)));
typedef float f32x4  __attribute__((ext_vector_type(4)));
typedef uint32_t u32x4 __attribute__((ext_vector_type(4)));

#define MFMA16(a,b,c) __builtin_amdgcn_mfma_f32_16x16x32_bf16((a),(b),(c),0,0,0)

#define B_    4096
#define S_    50
#define V_    50000
#define VP_   50048     // 782 * 64
#define KH    160       // padded h width (154 -> 160)
#define KY    640       // padded y1 width (616 -> 640)
#define KWP   168       // padded fc-weight row stride (elems)
#define BNF   64        // fc N-subtile rows
#define NSUB  782       // VP_/BNF
#define NCHUNK 32       // fc N-chunks (grid dim)
#define TILE_U16 (BNF * KWP)
#define TILE_LD  (TILE_U16 * 2 / 16)
#define LD_PER_T 6

static __device__ __forceinline__ u16 f2bf(float f) {
  union { float f; uint32_t u; } v; v.f = f;
  uint32_t u = v.u;
  return (u16)((u + 0x7FFFu + ((u >> 16) & 1u)) >> 16);   // RNE
}
static __device__ __forceinline__ float bf2f(u16 b) {
  union { uint32_t u; float f; } v; v.u = ((uint32_t)b) << 16; return v.f;
}

// ---------------- prep kernels ----------------

__global__ __launch_bounds__(256) void prep_fc_k(const float* __restrict__ fcw, u16* __restrict__ fcwb) {
  int e4 = (blockIdx.x * 256 + threadIdx.x) * 4;
  if (e4 >= VP_ * KWP) return;
  int v = e4 / KWP, c = e4 - v * KWP;
  u16 o[4];
  #pragma unroll
  for (int i = 0; i < 4; ++i) {
    float x = (v < V_ && (c + i) < 154) ? fcw[(size_t)v * 154 + c + i] : 0.f;
    o[i] = f2bf(x);
  }
  *(uint2*)(fcwb + e4) = make_uint2((uint32_t)o[0] | ((uint32_t)o[1] << 16),
                                    (uint32_t)o[2] | ((uint32_t)o[3] << 16));
}

__global__ __launch_bounds__(256) void prep_res_k(const float* __restrict__ rw1, const float* __restrict__ rw2,
                                                  u16* __restrict__ W1h, u16* __restrict__ W1l,
                                                  u16* __restrict__ W2h, u16* __restrict__ W2l) {
  int e = blockIdx.x * 256 + threadIdx.x;
  const int NW = 6 * KY * KH;
  if (e < NW) {
    int k = e % KH, n = (e / KH) % KY, i = e / (KH * KY);
    float x = (n < 616 && k < 154) ? rw1[((size_t)i * 616 + n) * 154 + k] : 0.f;
    u16 hi = f2bf(x);
    W1h[e] = hi; W1l[e] = f2bf(x - bf2f(hi));
  } else if (e < 2 * NW) {
    int e2 = e - NW;
    int k = e2 % KY, n = (e2 / KY) % KH, i = e2 / (KH * KY);
    float x = (n < 154 && k < 616) ? rw2[((size_t)i * 154 + n) * 616 + k] : 0.f;
    u16 hi = f2bf(x);
    W2h[e2] = hi; W2l[e2] = f2bf(x - bf2f(hi));
  }
}

__global__ __launch_bounds__(256) void prep_bias_k(const float* __restrict__ rb1, const float* __restrict__ rb2,
                                                   float* __restrict__ b1p, float* __restrict__ b2p) {
  int e = blockIdx.x * 256 + threadIdx.x;
  if (e < 6 * KY) {
    int i = e / KY, n = e % KY;
    b1p[e] = (n < 616) ? rb1[i * 616 + n] : 0.f;
  } else if (e < 6 * KY + 6 * KH) {
    int e2 = e - 6 * KY;
    int i = e2 / KH, n = e2 % KH;
    b2p[e2] = (n < 154) ? rb2[i * 154 + n] : 0.f;
  }
}

// ---------------- h0: embed gather + masked mean + SE gate ----------------

__global__ __launch_bounds__(192) void h0_k(const float* __restrict__ inp, const int* __restrict__ mask,
                                            const float* __restrict__ embed,
                                            const float* __restrict__ sw1, const float* __restrict__ sb1,
                                            const float* __restrict__ sw2, const float* __restrict__ sb2,
                                            u16* __restrict__ Hh, u16* __restrict__ Hl) {
  int b = blockIdx.x, t = threadIdx.x;
  __shared__ float in_s[S_ * 28];
  __shared__ int   ids[S_];
  __shared__ float h_s[160];
  __shared__ float means[6];
  __shared__ int   len_s;
  const float* row = inp + (size_t)b * S_ * 28;
  for (int i = t; i < S_ * 28; i += 192) in_s[i] = row[i];
  int msum = 0;
  if (t < S_) msum = mask[b * S_ + t];
  __syncthreads();
  if (t < 64) {
    for (int off = 32; off; off >>= 1) msum += __shfl_down(msum, off);
    if (t == 0) len_s = msum;
  }
  if (t < S_) ids[t] = (int)in_s[t * 28];
  __syncthreads();
  int len = len_s;
  if (t < 154) {
    float val;
    if (t < 77) {
      float s = 0.f;
      if (t < 50) { for (int si = 0; si < len; ++si) s += embed[(size_t)ids[si] * 50 + t]; }
      else        { for (int si = 0; si < len; ++si) s += in_s[si * 28 + 1 + (t - 50)]; }
      val = s / (float)len;
    } else {
      int k2 = t - 77;
      val = (k2 < 50) ? embed[(size_t)ids[S_ - 1] * 50 + k2] : in_s[(S_ - 1) * 28 + 1 + (k2 - 50)];
    }
    h_s[t] = val;
  }
  __syncthreads();
  if (t < 6) {
    const int bnd[7] = {0, 50, 56, 77, 127, 133, 154};
    float s = 0.f;
    for (int k = bnd[t]; k < bnd[t + 1]; ++k) s += h_s[k];
    means[t] = s / (float)(bnd[t + 1] - bnd[t]);
  }
  __syncthreads();
  if (t < 160) {
    float o = 0.f;
    if (t < 154) {
      int seg = (t < 50) ? 0 : (t < 56) ? 1 : (t < 77) ? 2 : (t < 127) ? 3 : (t < 133) ? 4 : 5;
      float r0 = sb1[0], r1 = sb1[1];
      #pragma unroll
      for (int j = 0; j < 6; ++j) { r0 += sw1[j] * means[j]; r1 += sw1[6 + j] * means[j]; }
      r0 = fmaxf(r0, 0.f); r1 = fmaxf(r1, 0.f);
      float z = sw2[seg * 2 + 0] * r0 + sw2[seg * 2 + 1] * r1 + sb2[seg];
      float gate = 1.f / (1.f + __expf(-z));
      o = h_s[t] * gate;
    }
    u16 hi = f2bf(o);
    size_t oi = (size_t)b * KH + t;
    Hh[oi] = hi;
    Hl[oi] = f2bf(o - bf2f(hi));
  }
}

// ---------------- fused trunk: 6 resblocks, h resident in LDS ----------------
// 128 blocks x 512 thr (8 waves), BM=32 rows/block.
// gemm1: y1 = relu(h@W1^T+b1)  : wave w -> nt in [w*5,w*5+5), both mt.  D=(n@lk*4+j, m@lr).
// gemm2: h += relu(y1@W2^T+b2) : wave w -> mt2=w&1, nt2 in {p,p+4,p+8}, p=w>>1.
// y1 in LDS swizzled: byte ^= (m&7)<<4.

__global__ __launch_bounds__(512, 2) void trunk_k(const u16* __restrict__ W1h_, const u16* __restrict__ W1l_,
                                                  const u16* __restrict__ W2h_, const u16* __restrict__ W2l_,
                                                  const float* __restrict__ b1p, const float* __restrict__ b2p,
                                                  u16* __restrict__ Hh, u16* __restrict__ Hl) {
  __shared__ __align__(16) u16 sHh[32 * 168], sHl[32 * 168];
  __shared__ __align__(16) u16 sYh[32 * 640], sYl[32 * 640];
  int t = threadIdx.x, mb = blockIdx.x;
  int w = t >> 6, lane = t & 63, lr = lane & 15, lk = lane >> 4;
  // load h tile (32 rows x 20 x 8-elem chunks)
  for (int c = t; c < 640; c += 512) {
    int r = c / 20, c8 = c - r * 20;
    *(uint4*)(sHh + r * 168 + c8 * 8) = *(const uint4*)(Hh + (size_t)(mb * 32 + r) * KH + c8 * 8);
    *(uint4*)(sHl + r * 168 + c8 * 8) = *(const uint4*)(Hl + (size_t)(mb * 32 + r) * KH + c8 * 8);
  }
  __syncthreads();
  int p = w >> 1, mt2 = w & 1;
  int ncnt = (p < 2) ? 3 : 2;
  for (int i = 0; i < 6; ++i) {
    const u16* w1h = W1h_ + (size_t)i * KY * KH;
    const u16* w1l = W1l_ + (size_t)i * KY * KH;
    const u16* w2h = W2h_ + (size_t)i * KH * KY;
    const u16* w2l = W2l_ + (size_t)i * KH * KY;
    const float* b1 = b1p + i * KY;
    const float* b2 = b2p + i * KH;
    // ---- gemm1 ----
    f32x4 acc1[2][5];
    #pragma unroll
    for (int mt = 0; mt < 2; ++mt)
      #pragma unroll
      for (int nti = 0; nti < 5; ++nti) acc1[mt][nti] = (f32x4){0.f,0.f,0.f,0.f};
    #pragma unroll
    for (int ks = 0; ks < 5; ++ks) {
      bf16x8 hh[2], hl[2];
      #pragma unroll
      for (int mt = 0; mt < 2; ++mt) {
        int ro = (mt * 16 + lr) * 168 + ks * 32 + lk * 8;
        hh[mt] = *(const bf16x8*)(sHh + ro);
        hl[mt] = *(const bf16x8*)(sHl + ro);
      }
      #pragma unroll
      for (int nti = 0; nti < 5; ++nti) {
        size_t go = (size_t)((w * 5 + nti) * 16 + lr) * KH + ks * 32 + lk * 8;
        bf16x8 wh = *(const bf16x8*)(w1h + go);
        bf16x8 wl = *(const bf16x8*)(w1l + go);
        #pragma unroll
        for (int mt = 0; mt < 2; ++mt) {
          acc1[mt][nti] = MFMA16(wh, hh[mt], acc1[mt][nti]);
          acc1[mt][nti] = MFMA16(wh, hl[mt], acc1[mt][nti]);
          acc1[mt][nti] = MFMA16(wl, hh[mt], acc1[mt][nti]);
        }
      }
    }
    // epilogue -> sY (swizzled)
    #pragma unroll
    for (int nti = 0; nti < 5; ++nti) {
      int n0 = (w * 5 + nti) * 16 + lk * 4;
      f32x4 bv = *(const f32x4*)(b1 + n0);
      #pragma unroll
      for (int mt = 0; mt < 2; ++mt) {
        int m = mt * 16 + lr;
        uint32_t hh_[4], ll_[4];
        #pragma unroll
        for (int j = 0; j < 4; ++j) {
          float v = fmaxf(acc1[mt][nti][j] + bv[j], 0.f);
          u16 hi = f2bf(v);
          hh_[j] = hi; ll_[j] = f2bf(v - bf2f(hi));
        }
        int off = (m * 1280 + n0 * 2) ^ ((m & 7) << 4);
        *(uint2*)((char*)sYh + off) = make_uint2(hh_[0] | (hh_[1] << 16), hh_[2] | (hh_[3] << 16));
        *(uint2*)((char*)sYl + off) = make_uint2(ll_[0] | (ll_[1] << 16), ll_[2] | (ll_[3] << 16));
      }
    }
    __syncthreads();
    // ---- gemm2 ----
    f32x4 acc2[3];
    #pragma unroll
    for (int q = 0; q < 3; ++q) acc2[q] = (f32x4){0.f,0.f,0.f,0.f};
    int m2 = mt2 * 16 + lr;
    #pragma unroll
    for (int ks2 = 0; ks2 < 20; ++ks2) {
      int yoff = (m2 * 1280 + ks2 * 64 + lk * 16) ^ ((m2 & 7) << 4);
      bf16x8 yh = *(const bf16x8*)((char*)sYh + yoff);
      bf16x8 yl = *(const bf16x8*)((char*)sYl + yoff);
      #pragma unroll
      for (int q = 0; q < 3; ++q) {
        if (q < ncnt) {
          size_t go = (size_t)((p + q * 4) * 16 + lr) * KY + ks2 * 32 + lk * 8;
          bf16x8 wh = *(const bf16x8*)(w2h + go);
          bf16x8 wl = *(const bf16x8*)(w2l + go);
          acc2[q] = MFMA16(wh, yh, acc2[q]);
          acc2[q] = MFMA16(wh, yl, acc2[q]);
          acc2[q] = MFMA16(wl, yh, acc2[q]);
        }
      }
    }
    // epilogue -> sH (+residual)
    #pragma unroll
    for (int q = 0; q < 3; ++q) {
      if (q < ncnt) {
        int n0 = (p + q * 4) * 16 + lk * 4;
        f32x4 bv = *(const f32x4*)(b2 + n0);
        u16* ph = sHh + m2 * 168 + n0;
        u16* pl = sHl + m2 * 168 + n0;
        uint2 oh = *(uint2*)ph, ol = *(uint2*)pl;
        u16 hs[4] = {(u16)(oh.x & 0xFFFF), (u16)(oh.x >> 16), (u16)(oh.y & 0xFFFF), (u16)(oh.y >> 16)};
        u16 ls[4] = {(u16)(ol.x & 0xFFFF), (u16)(ol.x >> 16), (u16)(ol.y & 0xFFFF), (u16)(ol.y >> 16)};
        uint32_t nh[4], nl[4];
        #pragma unroll
        for (int j = 0; j < 4; ++j) {
          float hold = bf2f(hs[j]) + bf2f(ls[j]);
          float v = hold + fmaxf(acc2[q][j] + bv[j], 0.f);
          u16 hi = f2bf(v);
          nh[j] = hi; nl[j] = f2bf(v - bf2f(hi));
        }
        *(uint2*)ph = make_uint2(nh[0] | (nh[1] << 16), nh[2] | (nh[3] << 16));
        *(uint2*)pl = make_uint2(nl[0] | (nl[1] << 16), nl[2] | (nl[3] << 16));
      }
    }
    __syncthreads();
  }
  // store h tile back
  for (int c = t; c < 640; c += 512) {
    int r = c / 20, c8 = c - r * 20;
    *(uint4*)(Hh + (size_t)(mb * 32 + r) * KH + c8 * 8) = *(const uint4*)(sHh + r * 168 + c8 * 8);
    *(uint4*)(Hl + (size_t)(mb * 32 + r) * KH + c8 * 8) = *(const uint4*)(sHl + r * 168 + c8 * 8);
  }
}

// ---------------- fc head: A-in-regs, W-streamed double-buffered LDS ----------------

static __device__ __forceinline__ void fc_load(const u16* __restrict__ g, u32x4* ld, int t) {
  #pragma unroll
  for (int q = 0; q < LD_PER_T; ++q) {
    int idx = t + q * 256;
    if (idx < TILE_LD) ld[q] = *(const u32x4*)(g + idx * 8);
  }
}
static __device__ __forceinline__ void fc_store(u16* __restrict__ s, const u32x4* ld, int t) {
  #pragma unroll
  for (int q = 0; q < LD_PER_T; ++q) {
    int idx = t + q * 256;
    if (idx < TILE_LD) *(u32x4*)(s + idx * 8) = ld[q];
  }
}

template<int PASS>
__global__ __launch_bounds__(256, 2) void fc_k(const u16* __restrict__ Ah, const u16* __restrict__ Wb,
                                               const float* __restrict__ fcb,
                                               float* __restrict__ partial, const float* __restrict__ invr,
                                               float* __restrict__ out) {
  __shared__ __align__(16) u16 sW[2][TILE_U16];
  int t = threadIdx.x;
  int mb = blockIdx.x & 15, nc = blockIdx.x >> 4;
  int w = t >> 6, lane = t & 63, lr = lane & 15, lk = lane >> 4;
  int arow = mb * 256 + w * 64;
  bf16x8 af[4][5];
  #pragma unroll
  for (int mt = 0; mt < 4; ++mt) {
    const u16* ap = Ah + (size_t)(arow + mt * 16 + lr) * KH;
    #pragma unroll
    for (int ks = 0; ks < 5; ++ks) af[mt][ks] = *(const bf16x8*)(ap + (ks * 4 + lk) * 8);
  }
  float iv[4];
  float racc[4] = {0.f, 0.f, 0.f, 0.f};
  if (PASS == 2) {
    #pragma unroll
    for (int mt = 0; mt < 4; ++mt) iv[mt] = invr[arow + mt * 16 + lr];
  }
  u32x4 ld[LD_PER_T];
  fc_load(Wb + (size_t)nc * TILE_U16, ld, t);
  fc_store(sW[0], ld, t);
  __syncthreads();
  int cur = 0;
  for (int nb = nc; nb < NSUB; nb += NCHUNK) {
    int nn = nb + NCHUNK;
    if (nn < NSUB) fc_load(Wb + (size_t)nn * TILE_U16, ld, t);
    f32x4 acc[4][4];
    #pragma unroll
    for (int mt = 0; mt < 4; ++mt)
      #pragma unroll
      for (int nt = 0; nt < 4; ++nt) acc[mt][nt] = (f32x4){0.f,0.f,0.f,0.f};
    const u16* sw = sW[cur];
    #pragma unroll
    for (int ks = 0; ks < 5; ++ks) {
      bf16x8 wf[4];
      #pragma unroll
      for (int nt = 0; nt < 4; ++nt)
        wf[nt] = *(const bf16x8*)(sw + (nt * 16 + lr) * KWP + (ks * 4 + lk) * 8);
      #pragma unroll
      for (int mt = 0; mt < 4; ++mt)
        #pragma unroll
        for (int nt = 0; nt < 4; ++nt)
          acc[mt][nt] = MFMA16(wf[nt], af[mt][ks], acc[mt][nt]);
    }
    #pragma unroll
    for (int nt = 0; nt < 4; ++nt) {
      int n0 = nb * 64 + nt * 16 + lk * 4;
      if (n0 < V_) {
        f32x4 bv = *(const f32x4*)(fcb + n0);
        if (PASS == 1) {
          #pragma unroll
          for (int mt = 0; mt < 4; ++mt) {
            racc[mt] += __expf(acc[mt][nt][0] + bv[0]) + __expf(acc[mt][nt][1] + bv[1])
                      + __expf(acc[mt][nt][2] + bv[2]) + __expf(acc[mt][nt][3] + bv[3]);
          }
        } else {
          #pragma unroll
          for (int mt = 0; mt < 4; ++mt) {
            f32x4 v;
            v[0] = __expf(acc[mt][nt][0] + bv[0]) * iv[mt];
            v[1] = __expf(acc[mt][nt][1] + bv[1]) * iv[mt];
            v[2] = __expf(acc[mt][nt][2] + bv[2]) * iv[mt];
            v[3] = __expf(acc[mt][nt][3] + bv[3]) * iv[mt];
            __builtin_nontemporal_store(v, (f32x4*)(out + (size_t)(arow + mt * 16 + lr) * V_ + n0));
          }
        }
      }
    }
    if (nn < NSUB) fc_store(sW[cur ^ 1], ld, t);
    __syncthreads();
    cur ^= 1;
  }
  if (PASS == 1) {
    #pragma unroll
    for (int mt = 0; mt < 4; ++mt) {
      float s = racc[mt];
      s += __shfl_xor(s, 16);
      s += __shfl_xor(s, 32);
      if (lk == 0) partial[(size_t)nc * B_ + arow + mt * 16 + lr] = s;
    }
  }
}

__global__ __launch_bounds__(256) void rowsum_k(const float* __restrict__ partial, float* __restrict__ invr) {
  int r = blockIdx.x * 256 + threadIdx.x;
  float s = 0.f;
  for (int nc = 0; nc < NCHUNK; ++nc) s += partial[(size_t)nc * B_ + r];
  invr[r] = 1.f / s;
}

// ---------------- launcher ----------------

extern "C" void kernel_launch(void* const* d_in, const int* in_sizes, int n_in,
                              void* d_out, int out_size, void* d_ws, size_t ws_size,
                              hipStream_t stream) {
  const float* inp   = (const float*)d_in[0];
  const int*   mask  = (const int*)d_in[1];
  const float* embed = (const float*)d_in[2];
  const float* sw1   = (const float*)d_in[3];
  const float* sb1   = (const float*)d_in[4];
  const float* sw2   = (const float*)d_in[5];
  const float* sb2   = (const float*)d_in[6];
  const float* rw1   = (const float*)d_in[7];
  const float* rb1   = (const float*)d_in[8];
  const float* rw2   = (const float*)d_in[9];
  const float* rb2   = (const float*)d_in[10];
  const float* fcw   = (const float*)d_in[11];
  const float* fcb   = (const float*)d_in[12];
  float* out = (float*)d_out;

  uint8_t* wsb = (uint8_t*)d_ws;
  size_t off = 0;
  auto alloc = [&](size_t bytes) { uint8_t* p = wsb + off; off += (bytes + 255) & ~(size_t)255; return p; };
  u16*   fcwb = (u16*)  alloc((size_t)VP_ * KWP * 2);
  u16*   W1h  = (u16*)  alloc((size_t)6 * KY * KH * 2);
  u16*   W1l  = (u16*)  alloc((size_t)6 * KY * KH * 2);
  u16*   W2h  = (u16*)  alloc((size_t)6 * KH * KY * 2);
  u16*   W2l  = (u16*)  alloc((size_t)6 * KH * KY * 2);
  float* b1p  = (float*)alloc((size_t)6 * KY * 4);
  float* b2p  = (float*)alloc((size_t)6 * KH * 4);
  u16*   Hh   = (u16*)  alloc((size_t)B_ * KH * 2);
  u16*   Hl   = (u16*)  alloc((size_t)B_ * KH * 2);
  float* part = (float*)alloc((size_t)NCHUNK * B_ * 4);
  float* invr = (float*)alloc((size_t)B_ * 4);

  prep_fc_k  <<<(VP_ * KWP / 4 + 255) / 256, 256, 0, stream>>>(fcw, fcwb);
  prep_res_k <<<(2 * 6 * KY * KH + 255) / 256, 256, 0, stream>>>(rw1, rw2, W1h, W1l, W2h, W2l);
  prep_bias_k<<<(6 * KY + 6 * KH + 255) / 256, 256, 0, stream>>>(rb1, rb2, b1p, b2p);
  h0_k       <<<B_, 192, 0, stream>>>(inp, mask, embed, sw1, sb1, sw2, sb2, Hh, Hl);
  trunk_k    <<<128, 512, 0, stream>>>(W1h, W1l, W2h, W2l, b1p, b2p, Hh, Hl);
  fc_k<1>  <<<16 * NCHUNK, 256, 0, stream>>>(Hh, fcwb, fcb, part, nullptr, nullptr);
  rowsum_k <<<B_ / 256, 256, 0, stream>>>(part, invr);
  fc_k<2>  <<<16 * NCHUNK, 256, 0, stream>>>(Hh, fcwb, fcb, nullptr, invr, out);
}